// Round 4
// baseline (454.740 us; speedup 1.0000x reference)
//
#include <hip/hip_runtime.h>
#include <hip/hip_bf16.h>
#include <math.h>

#define NN 1024
#define BB 4
#define HH 8
#define DD 256
#define LL 4
#define DKK 32
#define MM 4096
#define EPSF 1e-6f

typedef __attribute__((ext_vector_type(8))) short short8;
typedef __attribute__((ext_vector_type(4))) float f32x4;

__device__ __forceinline__ unsigned short f2bf(float f) {
    __hip_bfloat16 h = __float2bfloat16(f);
    return *(unsigned short*)&h;
}
__device__ __forceinline__ float bf2f(unsigned short u) {
    unsigned v = ((unsigned)u) << 16;
    return __builtin_bit_cast(float, v);
}

// ---------------------------------------------------------------------------
// Prologue: h = x + in_emb[deg_in] + out_emb[deg_out] + pos @ W_svd + b_svd
// ---------------------------------------------------------------------------
__global__ __launch_bounds__(256) void prologue_kernel(
    const float* __restrict__ x, const int* __restrict__ deg_in,
    const int* __restrict__ deg_out, const float* __restrict__ svd,
    const float* __restrict__ in_emb, const float* __restrict__ out_emb,
    const float* __restrict__ Wsvd, const float* __restrict__ bsvd,
    float* __restrict__ h, short* __restrict__ hb)
{
    int blk = blockIdx.x;            // b*N + n
    int n = blk & (NN - 1);
    int d = threadIdx.x;
    __shared__ float pos[32];
    if (d < 32) {
        float v = svd[n * 32 + d];
        pos[d] = (d < 16) ? v : -v;
    }
    __syncthreads();
    int di = deg_in[n], dou = deg_out[n];
    float acc = x[(size_t)blk * DD + d] + in_emb[(size_t)di * DD + d]
              + out_emb[(size_t)dou * DD + d] + bsvd[d];
#pragma unroll
    for (int j = 0; j < 32; ++j) acc += pos[j] * Wsvd[j * DD + d];
    h[(size_t)blk * DD + d] = acc;
    hb[(size_t)blk * DD + d] = (short)f2bf(acc);
}

// ---------------------------------------------------------------------------
// Merged prep: blocks [0,384) transpose+convert weights; [384,640) swizzle bias.
// ---------------------------------------------------------------------------
__global__ __launch_bounds__(256) void prep_kernel(
    const float* __restrict__ Wq, const float* __restrict__ Wk,
    const float* __restrict__ Wv, const float* __restrict__ Wa,
    const float* __restrict__ W1, const float* __restrict__ W2,
    short* __restrict__ Wt,
    const int* __restrict__ sp, const float* __restrict__ emb,
    short* __restrict__ bsw)
{
    __shared__ float t[64][65];
    int tid = threadIdx.x;
    int blk = blockIdx.x;
    if (blk < 384) {
        int z = blk >> 4, tile = blk & 15;
        int name = z >> 2;
        const float* srcs[6] = {Wq, Wk, Wv, Wa, W1, W2};
        const float* W = srcs[name] + (size_t)(z & 3) * DD * DD;
        short* dst = Wt + (size_t)z * DD * DD;
        int r0 = (tile >> 2) * 64, c0 = (tile & 3) * 64;
#pragma unroll
        for (int i = 0; i < 16; ++i) {
            int idx = i * 256 + tid;
            int r = idx >> 6, c = idx & 63;
            t[r][c] = W[(size_t)(r0 + r) * DD + c0 + c];
        }
        __syncthreads();
#pragma unroll
        for (int i = 0; i < 16; ++i) {
            int idx = i * 256 + tid;
            int n = idx >> 6, k = idx & 63;
            dst[(size_t)(c0 + n) * DD + r0 + k] = (short)f2bf(t[k][n]);
        }
    } else {
        int tt = (blk - 384) * 256 + tid;       // (q16, kt, lane)
        int lane = tt & 63, kt = (tt >> 6) & 15, q16 = tt >> 10;
        int quad = lane >> 4, c = lane & 15;
        unsigned buf[8][8];
#pragma unroll
        for (int j = 0; j < 16; ++j) {
            int f = j >> 2, r = j & 3;
            int row = q16 * 16 + quad * 4 + r;
            int col = kt * 64 + f * 16 + c;
            int p = sp[row * NN + col];
#pragma unroll
            for (int hh = 0; hh < 8; ++hh) {
                unsigned short u = f2bf(emb[p * 8 + hh]);
                if (j & 1) buf[hh][j >> 1] |= ((unsigned)u) << 16;
                else       buf[hh][j >> 1] = u;
            }
        }
#pragma unroll
        for (int hh = 0; hh < 8; ++hh) {
            uint4* dst = (uint4*)&bsw[(((size_t)hh * 64 + q16) * 16 + kt) * 1024 + (size_t)lane * 16];
            dst[0] = make_uint4(buf[hh][0], buf[hh][1], buf[hh][2], buf[hh][3]);
            dst[1] = make_uint4(buf[hh][4], buf[hh][5], buf[hh][6], buf[hh][7]);
        }
    }
}

// ---------------------------------------------------------------------------
// Plain bf16 MFMA GEMM + ReLU -> bf16 out (used for W1). Grid (64,4).
// ---------------------------------------------------------------------------
__global__ __launch_bounds__(256) void gemm_relu_kernel(
    const short* __restrict__ A, const short* __restrict__ Wt,
    const float* __restrict__ bias, short* __restrict__ outb)
{
    int tid = threadIdx.x, wave = tid >> 6, lane = tid & 63;
    int quad = lane >> 4, c = lane & 15;
    int m0 = blockIdx.x * 64 + wave * 16;
    int n0 = blockIdx.y * 64;

    f32x4 acc[4] = {{0.f,0.f,0.f,0.f},{0.f,0.f,0.f,0.f},
                    {0.f,0.f,0.f,0.f},{0.f,0.f,0.f,0.f}};
    const short* Ap = &A[(size_t)(m0 + c) * DD];
#pragma unroll
    for (int ks = 0; ks < 8; ++ks) {
        short8 af = *(const short8*)&Ap[ks * 32 + quad * 8];
#pragma unroll
        for (int f = 0; f < 4; ++f) {
            short8 bf = *(const short8*)&Wt[(size_t)(n0 + f * 16 + c) * DD + ks * 32 + quad * 8];
            acc[f] = __builtin_amdgcn_mfma_f32_16x16x32_bf16(af, bf, acc[f], 0, 0, 0);
        }
    }
#pragma unroll
    for (int f = 0; f < 4; ++f) {
        int col = n0 + f * 16 + c;
        float bv = bias[col];
#pragma unroll
        for (int r = 0; r < 4; ++r) {
            int row = m0 + quad * 4 + r;
            outb[(size_t)row * DD + col] = (short)f2bf(fmaxf(acc[f][r] + bv, 0.f));
        }
    }
}

// ---------------------------------------------------------------------------
// Fused GEMM + residual + LayerNorm.
// Block = 16 rows x 256 cols, 4 waves (wave w covers cols w*64..w*64+63).
// h_new = LN(h + A@Wt^T + bias) * g + lb; writes h (fp32) and hb (bf16).
// Grid: 256 blocks (MM/16).
// ---------------------------------------------------------------------------
__global__ __launch_bounds__(256) void gemm_ln_kernel(
    const short* __restrict__ A, const short* __restrict__ Wt,
    const float* __restrict__ bias, const float* __restrict__ g,
    const float* __restrict__ lb,
    float* __restrict__ h, short* __restrict__ hb)
{
    int tid = threadIdx.x, wave = tid >> 6, lane = tid & 63;
    int quad = lane >> 4, c = lane & 15;
    int m0 = blockIdx.x * 16;
    int n0 = wave * 64;

    f32x4 acc[4] = {{0.f,0.f,0.f,0.f},{0.f,0.f,0.f,0.f},
                    {0.f,0.f,0.f,0.f},{0.f,0.f,0.f,0.f}};
    const short* Ap = &A[(size_t)(m0 + c) * DD];
#pragma unroll
    for (int ks = 0; ks < 8; ++ks) {
        short8 af = *(const short8*)&Ap[ks * 32 + quad * 8];
#pragma unroll
        for (int f = 0; f < 4; ++f) {
            short8 bf = *(const short8*)&Wt[(size_t)(n0 + f * 16 + c) * DD + ks * 32 + quad * 8];
            acc[f] = __builtin_amdgcn_mfma_f32_16x16x32_bf16(af, bf, acc[f], 0, 0, 0);
        }
    }
    // residual add, then LN stats over the row (256 cols)
    float val[4][4];
    float ps[4], ps2[4];
#pragma unroll
    for (int r = 0; r < 4; ++r) { ps[r] = 0.f; ps2[r] = 0.f; }
#pragma unroll
    for (int f = 0; f < 4; ++f) {
        int col = n0 + f * 16 + c;
        float bv = bias[col];
#pragma unroll
        for (int r = 0; r < 4; ++r) {
            int row = m0 + quad * 4 + r;
            float v = h[(size_t)row * DD + col] + acc[f][r] + bv;
            val[f][r] = v;
            ps[r] += v;
            ps2[r] += v * v;
        }
    }
    // reduce across the 16 lanes of this quad (covers all 64 cols of the wave)
#pragma unroll
    for (int r = 0; r < 4; ++r) {
#pragma unroll
        for (int off = 1; off < 16; off <<= 1) {
            ps[r]  += __shfl_xor(ps[r], off);
            ps2[r] += __shfl_xor(ps2[r], off);
        }
    }
    __shared__ float shs[4][16][2];
    if (c == 0) {
#pragma unroll
        for (int r = 0; r < 4; ++r) {
            shs[wave][quad * 4 + r][0] = ps[r];
            shs[wave][quad * 4 + r][1] = ps2[r];
        }
    }
    __syncthreads();
    float mu[4], rvar[4];
#pragma unroll
    for (int r = 0; r < 4; ++r) {
        int rr = quad * 4 + r;
        float ts = shs[0][rr][0] + shs[1][rr][0] + shs[2][rr][0] + shs[3][rr][0];
        float t2 = shs[0][rr][1] + shs[1][rr][1] + shs[2][rr][1] + shs[3][rr][1];
        float m = ts * (1.0f / DD);
        mu[r] = m;
        rvar[r] = rsqrtf(t2 * (1.0f / DD) - m * m + EPSF);
    }
#pragma unroll
    for (int f = 0; f < 4; ++f) {
        int col = n0 + f * 16 + c;
        float gg = g[col], bbv = lb[col];
#pragma unroll
        for (int r = 0; r < 4; ++r) {
            int row = m0 + quad * 4 + r;
            float nv = (val[f][r] - mu[r]) * rvar[r] * gg + bbv;
            h[(size_t)row * DD + col] = nv;
            hb[(size_t)row * DD + col] = (short)f2bf(nv);
        }
    }
}

// ---------------------------------------------------------------------------
// QKV bf16 GEMM: z picks q/k/v. Q pre-scaled; Q,K -> [B*H,N,32]; V -> [B*H,32,N].
// ---------------------------------------------------------------------------
__global__ __launch_bounds__(256) void gemm_qkv_kernel(
    const short* __restrict__ A,
    const short* __restrict__ Wtq, const short* __restrict__ Wtk,
    const short* __restrict__ Wtv,
    const float* __restrict__ bq, const float* __restrict__ bk,
    const float* __restrict__ bv,
    short* __restrict__ qo, short* __restrict__ ko, short* __restrict__ vo)
{
    int z = blockIdx.z;
    const short* Wt = (z == 0) ? Wtq : (z == 1) ? Wtk : Wtv;
    const float* bs = (z == 0) ? bq : (z == 1) ? bk : bv;

    int tid = threadIdx.x, wave = tid >> 6, lane = tid & 63;
    int quad = lane >> 4, c = lane & 15;
    int m0 = blockIdx.x * 64 + wave * 16;
    int n0 = blockIdx.y * 64;

    f32x4 acc[4] = {{0.f,0.f,0.f,0.f},{0.f,0.f,0.f,0.f},
                    {0.f,0.f,0.f,0.f},{0.f,0.f,0.f,0.f}};
    const short* Ap = &A[(size_t)(m0 + c) * DD];
#pragma unroll
    for (int ks = 0; ks < 8; ++ks) {
        short8 af = *(const short8*)&Ap[ks * 32 + quad * 8];
#pragma unroll
        for (int f = 0; f < 4; ++f) {
            short8 bf = *(const short8*)&Wt[(size_t)(n0 + f * 16 + c) * DD + ks * 32 + quad * 8];
            acc[f] = __builtin_amdgcn_mfma_f32_16x16x32_bf16(af, bf, acc[f], 0, 0, 0);
        }
    }

    int b = m0 >> 10;
    int tok0 = (m0 & (NN - 1)) + quad * 4;
    const float scale = 0.17677669529663687f;   // 1/sqrt(32)

#pragma unroll
    for (int f = 0; f < 4; ++f) {
        int col = n0 + f * 16 + c;
        int head = col >> 5, dk = col & 31;
        int bh = b * 8 + head;
        float bv2 = bs[col];
        if (z == 2) {
            ushort4 pk;
            pk.x = f2bf(acc[f][0] + bv2);
            pk.y = f2bf(acc[f][1] + bv2);
            pk.z = f2bf(acc[f][2] + bv2);
            pk.w = f2bf(acc[f][3] + bv2);
            *(ushort4*)&vo[((size_t)bh * DKK + dk) * NN + tok0] = pk;
        } else {
            short* out = (z == 0) ? qo : ko;
            float sc = (z == 0) ? scale : 1.0f;
#pragma unroll
            for (int r = 0; r < 4; ++r)
                out[((size_t)bh * NN + tok0 + r) * DKK + dk] =
                    (short)f2bf((acc[f][r] + bv2) * sc);
        }
    }
}

// ---------------------------------------------------------------------------
// MFMA flash attention v2. Wave = one batch (4 waves = B); each wave does
// 32 Q rows (2 q16 tiles) for head blockIdx.y. Bias identical across waves
// (L1-served); K/V fragments shared across the 2 q16 tiles.
// Grid (NN/32, HH) = (32, 8).
// ---------------------------------------------------------------------------
__global__ __launch_bounds__(256) void attn_kernel(
    const short* __restrict__ q, const short* __restrict__ k,
    const short* __restrict__ vt, const short* __restrict__ bsw,
    short* __restrict__ o)
{
    int h = blockIdx.y;
    int tid = threadIdx.x, wave = tid >> 6, lane = tid & 63;
    int b = wave;
    int bh = b * 8 + h;
    int quad = lane >> 4, c = lane & 15;
    int q0 = blockIdx.x * 32;
    int t0 = blockIdx.x * 2;             // first q16 tile index

    __shared__ short Pl[4][2][16][72];

    short8 qf[2];
#pragma unroll
    for (int qt = 0; qt < 2; ++qt)
        qf[qt] = *(const short8*)&q[((size_t)bh * NN + q0 + qt * 16 + c) * DKK + quad * 8];

    float m_i[2][4], l_i[2][4];
    f32x4 Oa[2][2];
#pragma unroll
    for (int qt = 0; qt < 2; ++qt) {
#pragma unroll
        for (int r = 0; r < 4; ++r) { m_i[qt][r] = -1e30f; l_i[qt][r] = 0.f; }
        Oa[qt][0] = (f32x4){0.f, 0.f, 0.f, 0.f};
        Oa[qt][1] = (f32x4){0.f, 0.f, 0.f, 0.f};
    }
    const f32x4 zero = {0.f, 0.f, 0.f, 0.f};

    for (int kt = 0; kt < 16; ++kt) {
        // ---- K fragments (shared by both q-tiles) ----
        short8 kf[4];
#pragma unroll
        for (int f = 0; f < 4; ++f)
            kf[f] = *(const short8*)&k[((size_t)bh * NN + kt * 64 + f * 16 + c) * DKK + quad * 8];
        // ---- V fragments (shared by both q-tiles) ----
        short8 vf[2][2];
#pragma unroll
        for (int kc = 0; kc < 2; ++kc) {
            vf[kc][0] = *(const short8*)&vt[((size_t)bh * DKK + 0  + c) * NN + kt * 64 + kc * 32 + quad * 8];
            vf[kc][1] = *(const short8*)&vt[((size_t)bh * DKK + 16 + c) * NN + kt * 64 + kc * 32 + quad * 8];
        }
#pragma unroll
        for (int qt = 0; qt < 2; ++qt) {
            f32x4 s[4];
#pragma unroll
            for (int f = 0; f < 4; ++f)
                s[f] = __builtin_amdgcn_mfma_f32_16x16x32_bf16(qf[qt], kf[f], zero, 0, 0, 0);
            const short* bp = &bsw[(((size_t)h * 64 + t0 + qt) * 16 + kt) * 1024 + (size_t)lane * 16];
            short8 b0 = *(const short8*)bp;
            short8 b1 = *(const short8*)(bp + 8);
#pragma unroll
            for (int f = 0; f < 4; ++f)
#pragma unroll
                for (int r = 0; r < 4; ++r) {
                    int j = f * 4 + r;
                    unsigned short u = (unsigned short)((j < 8) ? b0[j] : b1[j - 8]);
                    s[f][r] += bf2f(u);
                }
#pragma unroll
            for (int r = 0; r < 4; ++r) {
                float mt = fmaxf(fmaxf(s[0][r], s[1][r]), fmaxf(s[2][r], s[3][r]));
#pragma unroll
                for (int off = 1; off < 16; off <<= 1) mt = fmaxf(mt, __shfl_xor(mt, off));
                float mn = fmaxf(m_i[qt][r], mt);
                float alpha = __expf(m_i[qt][r] - mn);
                m_i[qt][r] = mn;
                float rs = 0.f;
#pragma unroll
                for (int f = 0; f < 4; ++f) {
                    float p = __expf(s[f][r] - mn);
                    s[f][r] = p;
                    rs += p;
                }
#pragma unroll
                for (int off = 1; off < 16; off <<= 1) rs += __shfl_xor(rs, off);
                l_i[qt][r] = l_i[qt][r] * alpha + rs;
                Oa[qt][0][r] *= alpha;
                Oa[qt][1][r] *= alpha;
            }
            short (*P)[72] = Pl[wave][qt];
#pragma unroll
            for (int f = 0; f < 4; ++f)
#pragma unroll
                for (int r = 0; r < 4; ++r)
                    P[quad * 4 + r][f * 16 + c] = (short)f2bf(s[f][r]);
#pragma unroll
            for (int kc = 0; kc < 2; ++kc) {
                short8 pf = *(const short8*)&P[c][kc * 32 + quad * 8];
                Oa[qt][0] = __builtin_amdgcn_mfma_f32_16x16x32_bf16(pf, vf[kc][0], Oa[qt][0], 0, 0, 0);
                Oa[qt][1] = __builtin_amdgcn_mfma_f32_16x16x32_bf16(pf, vf[kc][1], Oa[qt][1], 0, 0, 0);
            }
        }
    }
#pragma unroll
    for (int qt = 0; qt < 2; ++qt)
#pragma unroll
        for (int r = 0; r < 4; ++r) {
            float inv = 1.0f / l_i[qt][r];
            int row = q0 + qt * 16 + quad * 4 + r;
            short* op = &o[((size_t)b * NN + row) * DD + h * DKK];
            op[c]      = (short)f2bf(Oa[qt][0][r] * inv);
            op[16 + c] = (short)f2bf(Oa[qt][1][r] * inv);
        }
}

// ---------------------------------------------------------------------------
extern "C" void kernel_launch(void* const* d_in, const int* in_sizes, int n_in,
                              void* d_out, int out_size, void* d_ws, size_t ws_size,
                              hipStream_t stream)
{
    const float* x       = (const float*)d_in[0];
    const int*   deg_in  = (const int*)d_in[1];
    const int*   deg_out = (const int*)d_in[2];
    const int*   sp      = (const int*)d_in[3];
    const float* svd     = (const float*)d_in[4];
    const float* in_emb  = (const float*)d_in[5];
    const float* out_emb = (const float*)d_in[6];
    const float* spemb   = (const float*)d_in[7];
    const float* Wsvd    = (const float*)d_in[8];
    const float* bsvd    = (const float*)d_in[9];
    const float* Wq = (const float*)d_in[10];
    const float* Wk = (const float*)d_in[11];
    const float* Wv = (const float*)d_in[12];
    const float* Wa = (const float*)d_in[13];
    const float* W1 = (const float*)d_in[14];
    const float* W2 = (const float*)d_in[15];
    const float* bq = (const float*)d_in[16];
    const float* bk = (const float*)d_in[17];
    const float* bv = (const float*)d_in[18];
    const float* ba = (const float*)d_in[19];
    const float* b1 = (const float*)d_in[20];
    const float* b2 = (const float*)d_in[21];
    const float* ln1b = (const float*)d_in[22];
    const float* ln2b = (const float*)d_in[23];
    const float* ln1g = (const float*)d_in[24];
    const float* ln2g = (const float*)d_in[25];

    float* h = (float*)d_out;
    char*  ws = (char*)d_ws;
    short* bias = (short*)ws;                         // 16 MB swizzled bf16 bias
    short* qb   = (short*)(ws + ((size_t)16 << 20));  // 2 MB bf16 [B*H,N,32]
    short* kb   = (short*)(ws + ((size_t)18 << 20));  // 2 MB
    short* vtb  = (short*)(ws + ((size_t)20 << 20));  // 2 MB bf16 [B*H,32,N]
    short* obb  = (short*)(ws + ((size_t)22 << 20));  // 2 MB bf16 attn out
    short* t1   = (short*)(ws + ((size_t)24 << 20));  // 2 MB bf16 relu out
    short* hb   = (short*)(ws + ((size_t)26 << 20));  // 2 MB bf16 shadow of h
    short* Wt   = (short*)(ws + ((size_t)28 << 20));  // 3 MB bf16 transposed W

    prologue_kernel<<<MM, 256, 0, stream>>>(x, deg_in, deg_out, svd, in_emb,
                                            out_emb, Wsvd, bsvd, h, hb);
    prep_kernel<<<640, 256, 0, stream>>>(Wq, Wk, Wv, Wa, W1, W2, Wt, sp, spemb, bias);

    const size_t WSZ = (size_t)DD * DD;
    for (int l = 0; l < LL; ++l) {
        const size_t bo = (size_t)l * DD;
        const short* Wtq = Wt + (0 * 4 + l) * WSZ;
        const short* Wtk = Wt + (1 * 4 + l) * WSZ;
        const short* Wtv = Wt + (2 * 4 + l) * WSZ;
        const short* Wta = Wt + (3 * 4 + l) * WSZ;
        const short* Wt1 = Wt + (4 * 4 + l) * WSZ;
        const short* Wt2 = Wt + (5 * 4 + l) * WSZ;

        gemm_qkv_kernel<<<dim3(MM / 64, DD / 64, 3), 256, 0, stream>>>(
            hb, Wtq, Wtk, Wtv, bq + bo, bk + bo, bv + bo, qb, kb, vtb);
        attn_kernel<<<dim3(NN / 32, HH), 256, 0, stream>>>(qb, kb, vtb, bias, obb);
        gemm_ln_kernel<<<MM / 16, 256, 0, stream>>>(
            obb, Wta, ba + bo, ln1g + bo, ln1b + bo, h, hb);
        gemm_relu_kernel<<<dim3(MM / 64, DD / 64), 256, 0, stream>>>(
            hb, Wt1, b1 + bo, t1);
        gemm_ln_kernel<<<MM / 16, 256, 0, stream>>>(
            t1, Wt2, b2 + bo, ln2g + bo, ln2b + bo, h, hb);
    }
}

// Round 5
// 447.357 us; speedup vs baseline: 1.0165x; 1.0165x over previous
//
#include <hip/hip_runtime.h>
#include <hip/hip_bf16.h>
#include <math.h>

#define NN 1024
#define BB 4
#define HH 8
#define DD 256
#define LL 4
#define DKK 32
#define MM 4096
#define EPSF 1e-6f

typedef __attribute__((ext_vector_type(8))) short short8;
typedef __attribute__((ext_vector_type(4))) float f32x4;

__device__ __forceinline__ unsigned short f2bf(float f) {
    __hip_bfloat16 h = __float2bfloat16(f);
    return *(unsigned short*)&h;
}
__device__ __forceinline__ float bf2f(unsigned short u) {
    unsigned v = ((unsigned)u) << 16;
    return __builtin_bit_cast(float, v);
}

// ---------------------------------------------------------------------------
// Prologue: h = x + in_emb[deg_in] + out_emb[deg_out] + pos @ W_svd + b_svd
// ---------------------------------------------------------------------------
__global__ __launch_bounds__(256) void prologue_kernel(
    const float* __restrict__ x, const int* __restrict__ deg_in,
    const int* __restrict__ deg_out, const float* __restrict__ svd,
    const float* __restrict__ in_emb, const float* __restrict__ out_emb,
    const float* __restrict__ Wsvd, const float* __restrict__ bsvd,
    float* __restrict__ h, short* __restrict__ hb)
{
    int blk = blockIdx.x;            // b*N + n
    int n = blk & (NN - 1);
    int d = threadIdx.x;
    __shared__ float pos[32];
    if (d < 32) {
        float v = svd[n * 32 + d];
        pos[d] = (d < 16) ? v : -v;
    }
    __syncthreads();
    int di = deg_in[n], dou = deg_out[n];
    float acc = x[(size_t)blk * DD + d] + in_emb[(size_t)di * DD + d]
              + out_emb[(size_t)dou * DD + d] + bsvd[d];
#pragma unroll
    for (int j = 0; j < 32; ++j) acc += pos[j] * Wsvd[j * DD + d];
    h[(size_t)blk * DD + d] = acc;
    hb[(size_t)blk * DD + d] = (short)f2bf(acc);
}

// ---------------------------------------------------------------------------
// Merged prep: blocks [0,384) transpose+convert weights; [384,640) swizzle bias.
// ---------------------------------------------------------------------------
__global__ __launch_bounds__(256) void prep_kernel(
    const float* __restrict__ Wq, const float* __restrict__ Wk,
    const float* __restrict__ Wv, const float* __restrict__ Wa,
    const float* __restrict__ W1, const float* __restrict__ W2,
    short* __restrict__ Wt,
    const int* __restrict__ sp, const float* __restrict__ emb,
    short* __restrict__ bsw)
{
    __shared__ float t[64][65];
    int tid = threadIdx.x;
    int blk = blockIdx.x;
    if (blk < 384) {
        int z = blk >> 4, tile = blk & 15;
        int name = z >> 2;
        const float* srcs[6] = {Wq, Wk, Wv, Wa, W1, W2};
        const float* W = srcs[name] + (size_t)(z & 3) * DD * DD;
        short* dst = Wt + (size_t)z * DD * DD;
        int r0 = (tile >> 2) * 64, c0 = (tile & 3) * 64;
#pragma unroll
        for (int i = 0; i < 16; ++i) {
            int idx = i * 256 + tid;
            int r = idx >> 6, c = idx & 63;
            t[r][c] = W[(size_t)(r0 + r) * DD + c0 + c];
        }
        __syncthreads();
#pragma unroll
        for (int i = 0; i < 16; ++i) {
            int idx = i * 256 + tid;
            int n = idx >> 6, k = idx & 63;
            dst[(size_t)(c0 + n) * DD + r0 + k] = (short)f2bf(t[k][n]);
        }
    } else {
        int tt = (blk - 384) * 256 + tid;       // (q16, kt, lane)
        int lane = tt & 63, kt = (tt >> 6) & 15, q16 = tt >> 10;
        int quad = lane >> 4, c = lane & 15;
        unsigned buf[8][8];
#pragma unroll
        for (int j = 0; j < 16; ++j) {
            int f = j >> 2, r = j & 3;
            int row = q16 * 16 + quad * 4 + r;
            int col = kt * 64 + f * 16 + c;
            int p = sp[row * NN + col];
#pragma unroll
            for (int hh = 0; hh < 8; ++hh) {
                unsigned short u = f2bf(emb[p * 8 + hh]);
                if (j & 1) buf[hh][j >> 1] |= ((unsigned)u) << 16;
                else       buf[hh][j >> 1] = u;
            }
        }
#pragma unroll
        for (int hh = 0; hh < 8; ++hh) {
            uint4* dst = (uint4*)&bsw[(((size_t)hh * 64 + q16) * 16 + kt) * 1024 + (size_t)lane * 16];
            dst[0] = make_uint4(buf[hh][0], buf[hh][1], buf[hh][2], buf[hh][3]);
            dst[1] = make_uint4(buf[hh][4], buf[hh][5], buf[hh][6], buf[hh][7]);
        }
    }
}

// ---------------------------------------------------------------------------
// bf16 GEMM + ReLU, wave = 16x16 tile. Grid (MM/16, 4). Waves share A-frag.
// ---------------------------------------------------------------------------
__global__ __launch_bounds__(256) void gemm_relu_kernel(
    const short* __restrict__ A, const short* __restrict__ Wt,
    const float* __restrict__ bias, short* __restrict__ outb)
{
    int tid = threadIdx.x, wave = tid >> 6, lane = tid & 63;
    int quad = lane >> 4, c = lane & 15;
    int m0 = blockIdx.x * 16;
    int n0 = blockIdx.y * 64 + wave * 16;

    f32x4 acc = {0.f, 0.f, 0.f, 0.f};
    const short* Ap = &A[(size_t)(m0 + c) * DD];
#pragma unroll
    for (int ks = 0; ks < 8; ++ks) {
        short8 af = *(const short8*)&Ap[ks * 32 + quad * 8];
        short8 bf = *(const short8*)&Wt[(size_t)(n0 + c) * DD + ks * 32 + quad * 8];
        acc = __builtin_amdgcn_mfma_f32_16x16x32_bf16(af, bf, acc, 0, 0, 0);
    }
    int col = n0 + c;
    float bv = bias[col];
#pragma unroll
    for (int r = 0; r < 4; ++r)
        outb[(size_t)(m0 + quad * 4 + r) * DD + col] = (short)f2bf(fmaxf(acc[r] + bv, 0.f));
}

// ---------------------------------------------------------------------------
// Fused GEMM + residual + LayerNorm. Block = 512 thr = 8 waves; wave covers
// 16 rows x 32 cols (2 col-frags). Grid MM/16 = 256 blocks.
// ---------------------------------------------------------------------------
__global__ __launch_bounds__(512) void gemm_ln_kernel(
    const short* __restrict__ A, const short* __restrict__ Wt,
    const float* __restrict__ bias, const float* __restrict__ g,
    const float* __restrict__ lb,
    float* __restrict__ h, short* __restrict__ hb)
{
    int tid = threadIdx.x, wave = tid >> 6, lane = tid & 63;
    int quad = lane >> 4, c = lane & 15;
    int m0 = blockIdx.x * 16;
    int n0 = wave * 32;

    f32x4 acc[2] = {{0.f,0.f,0.f,0.f},{0.f,0.f,0.f,0.f}};
    const short* Ap = &A[(size_t)(m0 + c) * DD];
#pragma unroll
    for (int ks = 0; ks < 8; ++ks) {
        short8 af = *(const short8*)&Ap[ks * 32 + quad * 8];
#pragma unroll
        for (int f = 0; f < 2; ++f) {
            short8 bf = *(const short8*)&Wt[(size_t)(n0 + f * 16 + c) * DD + ks * 32 + quad * 8];
            acc[f] = __builtin_amdgcn_mfma_f32_16x16x32_bf16(af, bf, acc[f], 0, 0, 0);
        }
    }
    float val[2][4];
    float ps[4] = {0.f,0.f,0.f,0.f}, ps2[4] = {0.f,0.f,0.f,0.f};
#pragma unroll
    for (int f = 0; f < 2; ++f) {
        int col = n0 + f * 16 + c;
        float bv = bias[col];
#pragma unroll
        for (int r = 0; r < 4; ++r) {
            int row = m0 + quad * 4 + r;
            float v = h[(size_t)row * DD + col] + acc[f][r] + bv;
            val[f][r] = v;
            ps[r] += v;
            ps2[r] += v * v;
        }
    }
#pragma unroll
    for (int r = 0; r < 4; ++r) {
#pragma unroll
        for (int off = 1; off < 16; off <<= 1) {
            ps[r]  += __shfl_xor(ps[r], off);
            ps2[r] += __shfl_xor(ps2[r], off);
        }
    }
    __shared__ float shs[8][16][2];
    if (c == 0) {
#pragma unroll
        for (int r = 0; r < 4; ++r) {
            shs[wave][quad * 4 + r][0] = ps[r];
            shs[wave][quad * 4 + r][1] = ps2[r];
        }
    }
    __syncthreads();
    float mu[4], rvar[4];
#pragma unroll
    for (int r = 0; r < 4; ++r) {
        int rr = quad * 4 + r;
        float ts = 0.f, t2 = 0.f;
#pragma unroll
        for (int w = 0; w < 8; ++w) { ts += shs[w][rr][0]; t2 += shs[w][rr][1]; }
        float m = ts * (1.0f / DD);
        mu[r] = m;
        rvar[r] = rsqrtf(t2 * (1.0f / DD) - m * m + EPSF);
    }
#pragma unroll
    for (int f = 0; f < 2; ++f) {
        int col = n0 + f * 16 + c;
        float gg = g[col], bbv = lb[col];
#pragma unroll
        for (int r = 0; r < 4; ++r) {
            int row = m0 + quad * 4 + r;
            float nv = (val[f][r] - mu[r]) * rvar[r] * gg + bbv;
            h[(size_t)row * DD + col] = nv;
            hb[(size_t)row * DD + col] = (short)f2bf(nv);
        }
    }
}

// ---------------------------------------------------------------------------
// QKV bf16 GEMM, wave = 16x16 tile. Grid (MM/16, 4, 3). Waves share A-frag.
// ---------------------------------------------------------------------------
__global__ __launch_bounds__(256) void gemm_qkv_kernel(
    const short* __restrict__ A,
    const short* __restrict__ Wtq, const short* __restrict__ Wtk,
    const short* __restrict__ Wtv,
    const float* __restrict__ bq, const float* __restrict__ bk,
    const float* __restrict__ bv,
    short* __restrict__ qo, short* __restrict__ ko, short* __restrict__ vo)
{
    int z = blockIdx.z;
    const short* Wt = (z == 0) ? Wtq : (z == 1) ? Wtk : Wtv;
    const float* bs = (z == 0) ? bq : (z == 1) ? bk : bv;

    int tid = threadIdx.x, wave = tid >> 6, lane = tid & 63;
    int quad = lane >> 4, c = lane & 15;
    int m0 = blockIdx.x * 16;
    int n0 = blockIdx.y * 64 + wave * 16;

    f32x4 acc = {0.f, 0.f, 0.f, 0.f};
    const short* Ap = &A[(size_t)(m0 + c) * DD];
#pragma unroll
    for (int ks = 0; ks < 8; ++ks) {
        short8 af = *(const short8*)&Ap[ks * 32 + quad * 8];
        short8 bf = *(const short8*)&Wt[(size_t)(n0 + c) * DD + ks * 32 + quad * 8];
        acc = __builtin_amdgcn_mfma_f32_16x16x32_bf16(af, bf, acc, 0, 0, 0);
    }

    int b = m0 >> 10;
    int tok0 = (m0 & (NN - 1)) + quad * 4;
    int col = n0 + c;
    int head = col >> 5, dk = col & 31;    // 16-col tile never straddles a head
    int bh = b * 8 + head;
    float bv2 = bs[col];
    const float scale = 0.17677669529663687f;   // 1/sqrt(32)

    if (z == 2) {
        ushort4 pk;
        pk.x = f2bf(acc[0] + bv2);
        pk.y = f2bf(acc[1] + bv2);
        pk.z = f2bf(acc[2] + bv2);
        pk.w = f2bf(acc[3] + bv2);
        *(ushort4*)&vo[((size_t)bh * DKK + dk) * NN + tok0] = pk;
    } else {
        short* out = (z == 0) ? qo : ko;
        float sc = (z == 0) ? scale : 1.0f;
#pragma unroll
        for (int r = 0; r < 4; ++r)
            out[((size_t)bh * NN + tok0 + r) * DKK + dk] =
                (short)f2bf((acc[r] + bv2) * sc);
    }
}

// ---------------------------------------------------------------------------
// MFMA flash attention v3: grid (64 q-tiles, 32 bh) = 2048 blocks.
// 4 waves split the K range (256 keys each, 4 kt-tiles of 64); partial
// (m, l, O) merged across waves via LDS at the end.
// ---------------------------------------------------------------------------
__global__ __launch_bounds__(256) void attn_kernel(
    const short* __restrict__ q, const short* __restrict__ k,
    const short* __restrict__ vt, const short* __restrict__ bsw,
    short* __restrict__ o)
{
    int bh = blockIdx.y;
    int b = bh >> 3, h = bh & 7;
    int t = blockIdx.x;                 // q16 tile index 0..63
    int tid = threadIdx.x, wave = tid >> 6, lane = tid & 63;
    int quad = lane >> 4, c = lane & 15;
    int q0 = t * 16;

    __shared__ short Pl[4][16][72];
    __shared__ float Om[4][16][32];
    __shared__ float Ml[4][16][2];
    short (*P)[72] = Pl[wave];

    short8 qf = *(const short8*)&q[((size_t)bh * NN + q0 + c) * DKK + quad * 8];

    float m_i[4], l_i[4];
    f32x4 Oa0 = {0.f, 0.f, 0.f, 0.f};
    f32x4 Oa1 = {0.f, 0.f, 0.f, 0.f};
#pragma unroll
    for (int r = 0; r < 4; ++r) { m_i[r] = -1e30f; l_i[r] = 0.f; }
    const f32x4 zero = {0.f, 0.f, 0.f, 0.f};

#pragma unroll
    for (int j = 0; j < 4; ++j) {
        int kti = wave * 4 + j;          // kt-tile index 0..15
        int kt = kti * 64;
        f32x4 s[4];
#pragma unroll
        for (int f = 0; f < 4; ++f) {
            short8 kf = *(const short8*)&k[((size_t)bh * NN + kt + f * 16 + c) * DKK + quad * 8];
            s[f] = __builtin_amdgcn_mfma_f32_16x16x32_bf16(qf, kf, zero, 0, 0, 0);
        }
        const short* bp = &bsw[(((size_t)h * 64 + t) * 16 + kti) * 1024 + (size_t)lane * 16];
        short8 b0 = *(const short8*)bp;
        short8 b1 = *(const short8*)(bp + 8);
#pragma unroll
        for (int f = 0; f < 4; ++f)
#pragma unroll
            for (int r = 0; r < 4; ++r) {
                int jj = f * 4 + r;
                unsigned short u = (unsigned short)((jj < 8) ? b0[jj] : b1[jj - 8]);
                s[f][r] += bf2f(u);
            }
#pragma unroll
        for (int r = 0; r < 4; ++r) {
            float mt = fmaxf(fmaxf(s[0][r], s[1][r]), fmaxf(s[2][r], s[3][r]));
#pragma unroll
            for (int off = 1; off < 16; off <<= 1) mt = fmaxf(mt, __shfl_xor(mt, off));
            float mn = fmaxf(m_i[r], mt);
            float alpha = __expf(m_i[r] - mn);
            m_i[r] = mn;
            float rs = 0.f;
#pragma unroll
            for (int f = 0; f < 4; ++f) {
                float p = __expf(s[f][r] - mn);
                s[f][r] = p;
                rs += p;
            }
#pragma unroll
            for (int off = 1; off < 16; off <<= 1) rs += __shfl_xor(rs, off);
            l_i[r] = l_i[r] * alpha + rs;
            Oa0[r] *= alpha;
            Oa1[r] *= alpha;
        }
#pragma unroll
        for (int f = 0; f < 4; ++f)
#pragma unroll
            for (int r = 0; r < 4; ++r)
                P[quad * 4 + r][f * 16 + c] = (short)f2bf(s[f][r]);
#pragma unroll
        for (int kc = 0; kc < 2; ++kc) {
            short8 pf = *(const short8*)&P[c][kc * 32 + quad * 8];
            short8 vf0 = *(const short8*)&vt[((size_t)bh * DKK + 0  + c) * NN + kt + kc * 32 + quad * 8];
            short8 vf1 = *(const short8*)&vt[((size_t)bh * DKK + 16 + c) * NN + kt + kc * 32 + quad * 8];
            Oa0 = __builtin_amdgcn_mfma_f32_16x16x32_bf16(pf, vf0, Oa0, 0, 0, 0);
            Oa1 = __builtin_amdgcn_mfma_f32_16x16x32_bf16(pf, vf1, Oa1, 0, 0, 0);
        }
    }
    // ---- write partials, merge across the 4 waves ----
    if (c == 0) {
#pragma unroll
        for (int r = 0; r < 4; ++r) {
            Ml[wave][quad * 4 + r][0] = m_i[r];
            Ml[wave][quad * 4 + r][1] = l_i[r];
        }
    }
#pragma unroll
    for (int r = 0; r < 4; ++r) {
        Om[wave][quad * 4 + r][c]      = Oa0[r];
        Om[wave][quad * 4 + r][16 + c] = Oa1[r];
    }
    __syncthreads();
    int row = tid >> 4;                  // 0..15
    float mg = fmaxf(fmaxf(Ml[0][row][0], Ml[1][row][0]),
                     fmaxf(Ml[2][row][0], Ml[3][row][0]));
    float sc[4], lg = 0.f;
#pragma unroll
    for (int w = 0; w < 4; ++w) {
        sc[w] = __expf(Ml[w][row][0] - mg);
        lg += Ml[w][row][1] * sc[w];
    }
    float invl = 1.0f / lg;
    int col0 = (tid & 15) * 2;
    float o0 = 0.f, o1 = 0.f;
#pragma unroll
    for (int w = 0; w < 4; ++w) {
        o0 += Om[w][row][col0] * sc[w];
        o1 += Om[w][row][col0 + 1] * sc[w];
    }
    ushort2 pk;
    pk.x = f2bf(o0 * invl);
    pk.y = f2bf(o1 * invl);
    *(ushort2*)&o[((size_t)b * NN + q0 + row) * DD + h * DKK + col0] = pk;
}

// ---------------------------------------------------------------------------
extern "C" void kernel_launch(void* const* d_in, const int* in_sizes, int n_in,
                              void* d_out, int out_size, void* d_ws, size_t ws_size,
                              hipStream_t stream)
{
    const float* x       = (const float*)d_in[0];
    const int*   deg_in  = (const int*)d_in[1];
    const int*   deg_out = (const int*)d_in[2];
    const int*   sp      = (const int*)d_in[3];
    const float* svd     = (const float*)d_in[4];
    const float* in_emb  = (const float*)d_in[5];
    const float* out_emb = (const float*)d_in[6];
    const float* spemb   = (const float*)d_in[7];
    const float* Wsvd    = (const float*)d_in[8];
    const float* bsvd    = (const float*)d_in[9];
    const float* Wq = (const float*)d_in[10];
    const float* Wk = (const float*)d_in[11];
    const float* Wv = (const float*)d_in[12];
    const float* Wa = (const float*)d_in[13];
    const float* W1 = (const float*)d_in[14];
    const float* W2 = (const float*)d_in[15];
    const float* bq = (const float*)d_in[16];
    const float* bk = (const float*)d_in[17];
    const float* bv = (const float*)d_in[18];
    const float* ba = (const float*)d_in[19];
    const float* b1 = (const float*)d_in[20];
    const float* b2 = (const float*)d_in[21];
    const float* ln1b = (const float*)d_in[22];
    const float* ln2b = (const float*)d_in[23];
    const float* ln1g = (const float*)d_in[24];
    const float* ln2g = (const float*)d_in[25];

    float* h = (float*)d_out;
    char*  ws = (char*)d_ws;
    short* bias = (short*)ws;                         // 16 MB swizzled bf16 bias
    short* qb   = (short*)(ws + ((size_t)16 << 20));  // 2 MB bf16 [B*H,N,32]
    short* kb   = (short*)(ws + ((size_t)18 << 20));  // 2 MB
    short* vtb  = (short*)(ws + ((size_t)20 << 20));  // 2 MB bf16 [B*H,32,N]
    short* obb  = (short*)(ws + ((size_t)22 << 20));  // 2 MB bf16 attn out
    short* t1   = (short*)(ws + ((size_t)24 << 20));  // 2 MB bf16 relu out
    short* hb   = (short*)(ws + ((size_t)26 << 20));  // 2 MB bf16 shadow of h
    short* Wt   = (short*)(ws + ((size_t)28 << 20));  // 3 MB bf16 transposed W

    prologue_kernel<<<MM, 256, 0, stream>>>(x, deg_in, deg_out, svd, in_emb,
                                            out_emb, Wsvd, bsvd, h, hb);
    prep_kernel<<<640, 256, 0, stream>>>(Wq, Wk, Wv, Wa, W1, W2, Wt, sp, spemb, bias);

    const size_t WSZ = (size_t)DD * DD;
    for (int l = 0; l < LL; ++l) {
        const size_t bo = (size_t)l * DD;
        const short* Wtq = Wt + (0 * 4 + l) * WSZ;
        const short* Wtk = Wt + (1 * 4 + l) * WSZ;
        const short* Wtv = Wt + (2 * 4 + l) * WSZ;
        const short* Wta = Wt + (3 * 4 + l) * WSZ;
        const short* Wt1 = Wt + (4 * 4 + l) * WSZ;
        const short* Wt2 = Wt + (5 * 4 + l) * WSZ;

        gemm_qkv_kernel<<<dim3(MM / 16, 4, 3), 256, 0, stream>>>(
            hb, Wtq, Wtk, Wtv, bq + bo, bk + bo, bv + bo, qb, kb, vtb);
        attn_kernel<<<dim3(NN / 16, BB * HH), 256, 0, stream>>>(qb, kb, vtb, bias, obb);
        gemm_ln_kernel<<<MM / 16, 512, 0, stream>>>(
            obb, Wta, ba + bo, ln1g + bo, ln1b + bo, h, hb);
        gemm_relu_kernel<<<dim3(MM / 16, 4), 256, 0, stream>>>(
            hb, Wt1, b1 + bo, t1);
        gemm_ln_kernel<<<MM / 16, 512, 0, stream>>>(
            t1, Wt2, b2 + bo, ln2g + bo, ln2b + bo, h, hb);
    }
}